// Round 8
// baseline (216.027 us; speedup 1.0000x reference)
//
#include <hip/hip_runtime.h>
#include <math.h>

#define NROWS 16384
#define DDIM  2048
#define EEXP  64
#define RB    64                 // rows per block -> grid 256, 1 block/CU
#define NST   8                  // stage-steps, 256 floats of k each
#define CHSTRIDE 24576           // wsplit: 4 kg * 2 et * 64 lanes * 48 B per chunk

typedef short        bf16x8 __attribute__((ext_vector_type(8)));
typedef float        f32x16 __attribute__((ext_vector_type(16)));
typedef float        f32x4  __attribute__((ext_vector_type(4)));
typedef unsigned int u32x4  __attribute__((ext_vector_type(4)));

union V4 { u32x4 u; bf16x8 s; };

// Truncating 3-way bf16 split: f = X0 + X1 + X2 + eps, |eps| <= 2^-24 |f|
static __device__ __forceinline__ void split3x2(float f0, float f1,
                                                unsigned int &p0, unsigned int &p1,
                                                unsigned int &p2) {
    unsigned int a0 = __float_as_uint(f0), b0 = __float_as_uint(f1);
    unsigned int ah = a0 & 0xffff0000u,   bh = b0 & 0xffff0000u;
    float fa1 = f0 - __uint_as_float(ah);
    float fb1 = f1 - __uint_as_float(bh);
    unsigned int a1 = __float_as_uint(fa1), b1 = __float_as_uint(fb1);
    unsigned int am = a1 & 0xffff0000u,     bm = b1 & 0xffff0000u;
    float fa2 = fa1 - __uint_as_float(am);
    float fb2 = fb1 - __uint_as_float(bm);
    p0 = (a0 >> 16) | bh;
    p1 = (a1 >> 16) | bm;
    p2 = (__float_as_uint(fa2) >> 16) | (__float_as_uint(fb2) & 0xffff0000u);
}

static __device__ __forceinline__ void cvt8(f32x4 u, f32x4 v, V4 &q0, V4 &q1, V4 &q2) {
    unsigned int a, b, c;
    split3x2(u[0], u[1], a, b, c); q0.u[0] = a; q1.u[0] = b; q2.u[0] = c;
    split3x2(u[2], u[3], a, b, c); q0.u[1] = a; q1.u[1] = b; q2.u[1] = c;
    split3x2(v[0], v[1], a, b, c); q0.u[2] = a; q1.u[2] = b; q2.u[2] = c;
    split3x2(v[2], v[3], a, b, c); q0.u[3] = a; q1.u[3] = b; q2.u[3] = c;
}

#define MM(ACC, A, B) ACC = __builtin_amdgcn_mfma_f32_32x32x16_bf16((A), (B), ACC, 0, 0, 0)

// ---- prep: W [2048][64] fp32 -> fragment-ordered 3-level bf16 split (as R5/R6) ----
__global__ __launch_bounds__(256)
void wsplit_kernel(const float* __restrict__ W, unsigned char* __restrict__ ws) {
    const int t  = blockIdx.x * 256 + threadIdx.x;
    const int e  = t & 63;
    const int ko = t >> 6;
    const int k0 = ko * 8;
    f32x4 u, v;
#pragma unroll
    for (int j = 0; j < 4; ++j) u[j] = W[(size_t)(k0 + j) * EEXP + e];
#pragma unroll
    for (int j = 0; j < 4; ++j) v[j] = W[(size_t)(k0 + 4 + j) * EEXP + e];
    V4 q0, q1, q2;
    cvt8(u, v, q0, q1, q2);
    const int c  = k0 >> 6;
    const int kg = (k0 >> 4) & 3;
    const int h  = (k0 >> 3) & 1;
    const int et = e >> 5;
    const int ln = h * 32 + (e & 31);
    unsigned char* d = ws + (size_t)(((((c * 4 + kg) * 2 + et) * 64) + ln) * 48);
    *(u32x4*)(d +  0) = q0.u;
    *(u32x4*)(d + 16) = q1.u;
    *(u32x4*)(d + 32) = q2.u;
}

__global__ __launch_bounds__(512, 2)
void router_kernel(const float* __restrict__ x,
                   const unsigned char* __restrict__ wsplit,
                   const float* __restrict__ bias_v,
                   float* __restrict__ mask_out,
                   float* __restrict__ idx_out) {
    // x tile: [2 bufs][64 rows][256 floats] = 128 KB; epilogue (64 KB) overlays buf0
    __shared__ __align__(16) float smem[32768];

    const int tid  = threadIdx.x;
    const int lane = tid & 63;
    const int w    = __builtin_amdgcn_readfirstlane(tid >> 6);
    const int kg   = w & 3;
    const int et   = w >> 2;
    const int l31  = lane & 31;
    const int h    = lane >> 5;

    // XCD-aware bijective swizzle (256 % 8 == 0)
    const int bid  = blockIdx.x;
    const int bswz = (bid & 7) * ((int)gridDim.x >> 3) + (bid >> 3);
    const int row0 = bswz * RB;
    // K-phase stagger: decorrelate column bands across blocks
    const int s0   = bswz & 7;

    // staging: wave w owns rows 8w..8w+7; lane reads 16 B at +lane*16 -> 1 KB/row
    const int srow = 8 * w;

    // B stream base (layout identical to R5/R6; chunk c = sr*4+cc)
    const unsigned char* wp = wsplit + (size_t)(((kg * 2 + et) * 64 + lane) * 48);

    f32x16 accA, accB, accC, accD;   // (tile0: A,B) (tile1: C,D)
#pragma unroll
    for (int i = 0; i < 16; ++i) { accA[i] = 0.f; accB[i] = 0.f; accC[i] = 0.f; accD[i] = 0.f; }

#define XWR(I, V, B, SR_ROW_BASE)                                             \
    *(f32x4*)(smem + (B) * 16384 + (SR_ROW_BASE + I) * 256 +                  \
              ((lane ^ ((SR_ROW_BASE + I) & 7)) << 2)) = V;

    // ---- prologue: stage s0 into buf0 (8 rows/wave, 1 KB contiguous each) ----
    {
        const float* xs = x + (size_t)s0 * 256 + lane * 4;
        f32x4 X0 = *(const f32x4*)(xs + (size_t)(row0 + srow + 0) * DDIM);
        f32x4 X1 = *(const f32x4*)(xs + (size_t)(row0 + srow + 1) * DDIM);
        f32x4 X2 = *(const f32x4*)(xs + (size_t)(row0 + srow + 2) * DDIM);
        f32x4 X3 = *(const f32x4*)(xs + (size_t)(row0 + srow + 3) * DDIM);
        f32x4 X4 = *(const f32x4*)(xs + (size_t)(row0 + srow + 4) * DDIM);
        f32x4 X5 = *(const f32x4*)(xs + (size_t)(row0 + srow + 5) * DDIM);
        f32x4 X6 = *(const f32x4*)(xs + (size_t)(row0 + srow + 6) * DDIM);
        f32x4 X7 = *(const f32x4*)(xs + (size_t)(row0 + srow + 7) * DDIM);
        XWR(0, X0, 0, srow) XWR(1, X1, 0, srow) XWR(2, X2, 0, srow) XWR(3, X3, 0, srow)
        XWR(4, X4, 0, srow) XWR(5, X5, 0, srow) XWR(6, X6, 0, srow) XWR(7, X7, 0, srow)
    }
    __syncthreads();

#pragma unroll 1
    for (int s = 0; s < NST; ++s) {
        const int  buf  = s & 1;
        const int  sr   = (s0 + s) & 7;          // staggered stage index
        const bool more = (s + 1) < NST;

        f32x4 X0, X1, X2, X3, X4, X5, X6, X7;
        if (more) {   // prefetch next (staggered) stage: 1 KB bursts
            const int srn = (s0 + s + 1) & 7;
            const float* xs = x + (size_t)srn * 256 + lane * 4;
            X0 = *(const f32x4*)(xs + (size_t)(row0 + srow + 0) * DDIM);
            X1 = *(const f32x4*)(xs + (size_t)(row0 + srow + 1) * DDIM);
            X2 = *(const f32x4*)(xs + (size_t)(row0 + srow + 2) * DDIM);
            X3 = *(const f32x4*)(xs + (size_t)(row0 + srow + 3) * DDIM);
            X4 = *(const f32x4*)(xs + (size_t)(row0 + srow + 4) * DDIM);
            X5 = *(const f32x4*)(xs + (size_t)(row0 + srow + 5) * DDIM);
            X6 = *(const f32x4*)(xs + (size_t)(row0 + srow + 6) * DDIM);
            X7 = *(const f32x4*)(xs + (size_t)(row0 + srow + 7) * DDIM);
        }

        // consume 4 chunks (KC=64) of stage sr from LDS; two row-tiles per wave
        const float* xb0 = smem + buf * 16384 + l31 * 256;          // rows 0..31
        const float* xb1 = xb0 + 32 * 256;                          // rows 32..63
        const int xr = l31 & 7;                                     // (row&7), same for row+32
#pragma unroll
        for (int cc = 0; cc < 4; ++cc) {
            const int k0 = cc * 64 + kg * 16 + h * 8;
            const int bb = k0 >> 2;                    // even 16B-block index
            f32x4 lo0 = *(const f32x4*)(xb0 + (((bb    ) ^ xr) << 2));
            f32x4 hi0 = *(const f32x4*)(xb0 + (((bb + 1) ^ xr) << 2));
            f32x4 lo1 = *(const f32x4*)(xb1 + (((bb    ) ^ xr) << 2));
            f32x4 hi1 = *(const f32x4*)(xb1 + (((bb + 1) ^ xr) << 2));
            const unsigned char* q = wp + (size_t)(sr * 4 + cc) * CHSTRIDE;
            V4 b0, b1, b2;
            b0.u = *(const u32x4*)(q);
            b1.u = *(const u32x4*)(q + 16);
            b2.u = *(const u32x4*)(q + 32);
            V4 a0, a1, a2;
            cvt8(lo0, hi0, a0, a1, a2);
            MM(accA, a0.s, b0.s); MM(accB, a0.s, b1.s); MM(accA, a1.s, b0.s);
            MM(accB, a0.s, b2.s); MM(accA, a1.s, b1.s); MM(accB, a2.s, b0.s);
            cvt8(lo1, hi1, a0, a1, a2);
            MM(accC, a0.s, b0.s); MM(accD, a0.s, b1.s); MM(accC, a1.s, b0.s);
            MM(accD, a0.s, b2.s); MM(accC, a1.s, b1.s); MM(accD, a2.s, b0.s);
        }

        if (more) {   // write next stage into the other buffer
            const int nb = buf ^ 1;
            XWR(0, X0, nb, srow) XWR(1, X1, nb, srow) XWR(2, X2, nb, srow) XWR(3, X3, nb, srow)
            XWR(4, X4, nb, srow) XWR(5, X5, nb, srow) XWR(6, X6, nb, srow) XWR(7, X7, nb, srow)
        }
        __syncthreads();
    }

    // ---- epilogue: reduce 4 kg-partials, softmax + top2 over 64 rows ----
    // C/D layout: col = lane&31, row = (reg&3) + 8*(reg>>2) + 4*(lane>>5)
    float* ep = smem;   // [kg][64 rows][64 e] = 64 KB
#pragma unroll
    for (int r = 0; r < 16; ++r) {
        const int rowl = (r & 3) + 8 * (r >> 2) + 4 * h;
        ep[kg * 4096 + rowl * 64 + et * 32 + l31]        = accA[r] + accB[r];
        ep[kg * 4096 + (rowl + 32) * 64 + et * 32 + l31] = accC[r] + accD[r];
    }
    __syncthreads();

    const float bias = bias_v[lane];
#pragma unroll
    for (int rr = 0; rr < 8; ++rr) {
        const int rl  = w * 8 + rr;            // 0..63 local row
        const int row = row0 + rl;
        float logit = bias + ep[rl * 64 + lane]
                           + ep[4096  + rl * 64 + lane]
                           + ep[8192  + rl * 64 + lane]
                           + ep[12288 + rl * 64 + lane];

        float m = logit;
#pragma unroll
        for (int off = 32; off >= 1; off >>= 1) m = fmaxf(m, __shfl_xor(m, off));
        float ex = __expf(logit - m);
        float s = ex;
#pragma unroll
        for (int off = 32; off >= 1; off >>= 1) s += __shfl_xor(s, off);
        float gate = ex / s;

        float v1 = logit; int i1 = lane;
#pragma unroll
        for (int off = 32; off >= 1; off >>= 1) {
            float ov = __shfl_xor(v1, off);
            int   oi = __shfl_xor(i1, off);
            if (ov > v1 || (ov == v1 && oi < i1)) { v1 = ov; i1 = oi; }
        }
        float v2 = (lane == i1) ? -INFINITY : logit; int i2 = lane;
#pragma unroll
        for (int off = 32; off >= 1; off >>= 1) {
            float ov = __shfl_xor(v2, off);
            int   oi = __shfl_xor(i2, off);
            if (ov > v2 || (ov == v2 && oi < i2)) { v2 = ov; i2 = oi; }
        }

        float outv = (lane == i1 || lane == i2) ? gate : 0.0f;
        mask_out[(size_t)row * EEXP + lane] = outv;
        if (lane == 0) {
            idx_out[row * 2 + 0] = (float)i1;
            idx_out[row * 2 + 1] = (float)i2;
        }
    }
}

extern "C" void kernel_launch(void* const* d_in, const int* in_sizes, int n_in,
                              void* d_out, int out_size, void* d_ws, size_t ws_size,
                              hipStream_t stream) {
    const float* x = (const float*)d_in[0];
    const float* W = (const float*)d_in[1];
    const float* b = (const float*)d_in[2];
    float* mask_out = (float*)d_out;
    float* idx_out  = mask_out + (size_t)NROWS * EEXP;
    unsigned char* ws = (unsigned char*)d_ws;   // needs 768 KB

    wsplit_kernel<<<dim3(64), dim3(256), 0, stream>>>(W, ws);
    router_kernel<<<dim3(NROWS / RB), dim3(512), 0, stream>>>(x, ws, b, mask_out, idx_out);
}

// Round 9
// 207.834 us; speedup vs baseline: 1.0394x; 1.0394x over previous
//
#include <hip/hip_runtime.h>
#include <math.h>

#define NROWS 16384
#define DDIM  2048
#define EEXP  64
#define RB    32                 // rows per block -> grid 512, 2 blocks/CU (R6 geometry)
#define NST   8                  // stage-steps, 256 floats of k each
#define CHSTRIDE 24576           // ws bytes per chunk: 8 pages * 3 lvl * 1KB

typedef short        bf16x8 __attribute__((ext_vector_type(8)));
typedef float        f32x16 __attribute__((ext_vector_type(16)));
typedef float        f32x4  __attribute__((ext_vector_type(4)));
typedef unsigned int u32x4  __attribute__((ext_vector_type(4)));

union V4 { u32x4 u; bf16x8 s; };

// Truncating 3-way bf16 split: f = X0 + X1 + X2 + eps, |eps| <= 2^-24 |f|
static __device__ __forceinline__ void split3x2(float f0, float f1,
                                                unsigned int &p0, unsigned int &p1,
                                                unsigned int &p2) {
    unsigned int a0 = __float_as_uint(f0), b0 = __float_as_uint(f1);
    unsigned int ah = a0 & 0xffff0000u,   bh = b0 & 0xffff0000u;
    float fa1 = f0 - __uint_as_float(ah);
    float fb1 = f1 - __uint_as_float(bh);
    unsigned int a1 = __float_as_uint(fa1), b1 = __float_as_uint(fb1);
    unsigned int am = a1 & 0xffff0000u,     bm = b1 & 0xffff0000u;
    float fa2 = fa1 - __uint_as_float(am);
    float fb2 = fb1 - __uint_as_float(bm);
    p0 = (a0 >> 16) | bh;
    p1 = (a1 >> 16) | bm;
    p2 = (__float_as_uint(fa2) >> 16) | (__float_as_uint(fb2) & 0xffff0000u);
}

static __device__ __forceinline__ void cvt8(f32x4 u, f32x4 v, V4 &q0, V4 &q1, V4 &q2) {
    unsigned int a, b, c;
    split3x2(u[0], u[1], a, b, c); q0.u[0] = a; q1.u[0] = b; q2.u[0] = c;
    split3x2(u[2], u[3], a, b, c); q0.u[1] = a; q1.u[1] = b; q2.u[1] = c;
    split3x2(v[0], v[1], a, b, c); q0.u[2] = a; q1.u[2] = b; q2.u[2] = c;
    split3x2(v[2], v[3], a, b, c); q0.u[3] = a; q1.u[3] = b; q2.u[3] = c;
}

#define MM(ACC, A, B) ACC = __builtin_amdgcn_mfma_f32_32x32x16_bf16((A), (B), ACC, 0, 0, 0)

// ---- prep: W -> per-(chunk,kg,et,lvl) 1KB pages, lane-contiguous 16B slots ----
// page(c,kg,et,lvl) at ((c*8 + kg*2 + et)*3 + lvl)*1024; slot = ln*16
__global__ __launch_bounds__(256)
void wsplit_kernel(const float* __restrict__ W, unsigned char* __restrict__ ws) {
    const int t  = blockIdx.x * 256 + threadIdx.x;
    const int e  = t & 63;
    const int ko = t >> 6;
    const int k0 = ko * 8;
    f32x4 u, v;
#pragma unroll
    for (int j = 0; j < 4; ++j) u[j] = W[(size_t)(k0 + j) * EEXP + e];
#pragma unroll
    for (int j = 0; j < 4; ++j) v[j] = W[(size_t)(k0 + 4 + j) * EEXP + e];
    V4 q0, q1, q2;
    cvt8(u, v, q0, q1, q2);
    const int c  = ko >> 3;
    const int kg = (ko >> 1) & 3;
    const int h  = ko & 1;
    const int et = e >> 5;
    const int ln = h * 32 + (e & 31);
    unsigned char* d = ws + (size_t)((c * 8 + kg * 2 + et) * 3) * 1024 + ln * 16;
    *(u32x4*)(d +    0) = q0.u;
    *(u32x4*)(d + 1024) = q1.u;
    *(u32x4*)(d + 2048) = q2.u;
}

__global__ __launch_bounds__(512, 2)
void router_kernel(const float* __restrict__ x,
                   const unsigned char* __restrict__ wsplit,
                   const float* __restrict__ bias_v,
                   float* __restrict__ mask_out,
                   float* __restrict__ idx_out) {
    // x tile: [2 bufs][32 rows][256 floats] = 64 KB; epilogue (32 KB) overlays buf0
    __shared__ __align__(16) float smem[16384];

    const int tid  = threadIdx.x;
    const int lane = tid & 63;
    const int w    = __builtin_amdgcn_readfirstlane(tid >> 6);
    const int kg   = w & 3;
    const int et   = w >> 2;
    const int l31  = lane & 31;
    const int h    = lane >> 5;

    // XCD-aware bijective swizzle (512 % 8 == 0)
    const int bid  = blockIdx.x;
    const int bswz = (bid & 7) * ((int)gridDim.x >> 3) + (bid >> 3);
    const int row0 = bswz * RB;

    const int srow = 4 * w;          // wave stages rows srow..srow+3

    // x staging via global_load_lds width=16: LINEAR LDS dest (wave-uniform base
    // + lane*16), PRE-SWIZZLED global source (lane ^ (row&7)) -> LDS image is
    // bit-identical to R6's XWR (position p holds global 16B-block p^(row&7)).
#define GLL(I, BAND, BUF)                                                     \
    __builtin_amdgcn_global_load_lds(                                         \
        (const __attribute__((address_space(1))) void*)                       \
            (x + (size_t)(row0 + srow + (I)) * DDIM + (BAND)                  \
               + ((lane ^ ((srow + (I)) & 7)) << 2)),                         \
        (__attribute__((address_space(3))) void*)                             \
            (smem + (BUF) * 8192 + (srow + (I)) * 256),                       \
        16, 0, 0);

    // B stream: every load = 64 lanes x 16B contiguous 1KB page
    const unsigned char* wq = wsplit + (size_t)((kg * 2 + et) * 3) * 1024 + lane * 16;

    f32x16 accA, accB;
#pragma unroll
    for (int i = 0; i < 16; ++i) { accA[i] = 0.f; accB[i] = 0.f; }

    // ---- prologue: stage 0 into buf0 ----
    GLL(0, 0, 0) GLL(1, 0, 0) GLL(2, 0, 0) GLL(3, 0, 0)
    __syncthreads();

#pragma unroll 1
    for (int s = 0; s < NST; ++s) {
        const int buf = s & 1;

        if (s + 1 < NST) {   // issue next stage early (fire-and-forget DMA)
            const int band = (s + 1) * 256;
            const int nb = buf ^ 1;
            GLL(0, band, nb) GLL(1, band, nb) GLL(2, band, nb) GLL(3, band, nb)
        }

        // consume 4 chunks (KC=64) of this stage from LDS
        const float* xb = smem + buf * 8192 + l31 * 256;
        const int xr = l31 & 7;
#pragma unroll
        for (int cc = 0; cc < 4; ++cc) {
            const int k0 = cc * 64 + kg * 16 + h * 8;
            const int bb = k0 >> 2;                    // even 16B-block index
            f32x4 lo = *(const f32x4*)(xb + (((bb    ) ^ xr) << 2));
            f32x4 hi = *(const f32x4*)(xb + (((bb + 1) ^ xr) << 2));
            const unsigned char* q = wq + (size_t)(s * 4 + cc) * CHSTRIDE;
            V4 b0, b1, b2;
            b0.u = *(const u32x4*)(q);
            b1.u = *(const u32x4*)(q + 1024);
            b2.u = *(const u32x4*)(q + 2048);
            V4 a0, a1, a2;
            cvt8(lo, hi, a0, a1, a2);
            MM(accA, a0.s, b0.s); MM(accB, a0.s, b1.s); MM(accA, a1.s, b0.s);
            MM(accB, a0.s, b2.s); MM(accA, a1.s, b1.s); MM(accB, a2.s, b0.s);
        }

        __syncthreads();   // drains the gload_lds for buf^1; buf swap safe
    }

    // ---- epilogue: reduce 4 kg-partials, softmax + top2 (R6-identical) ----
    // C/D layout: col = lane&31, row = (reg&3) + 8*(reg>>2) + 4*(lane>>5)
    float* ep = smem;    // [kg][32 rows][64 e] = 32 KB
#pragma unroll
    for (int r = 0; r < 16; ++r) {
        const int rowl = (r & 3) + 8 * (r >> 2) + 4 * h;
        ep[kg * 2048 + rowl * 64 + et * 32 + l31] = accA[r] + accB[r];
    }
    __syncthreads();

    const float bias = bias_v[lane];
#pragma unroll
    for (int rr = 0; rr < 4; ++rr) {
        const int rl  = w * 4 + rr;            // 0..31 local row
        const int row = row0 + rl;
        float logit = bias + ep[rl * 64 + lane]
                           + ep[2048 + rl * 64 + lane]
                           + ep[4096 + rl * 64 + lane]
                           + ep[6144 + rl * 64 + lane];

        float m = logit;
#pragma unroll
        for (int off = 32; off >= 1; off >>= 1) m = fmaxf(m, __shfl_xor(m, off));
        float ex = __expf(logit - m);
        float s = ex;
#pragma unroll
        for (int off = 32; off >= 1; off >>= 1) s += __shfl_xor(s, off);
        float gate = ex / s;

        float v1 = logit; int i1 = lane;
#pragma unroll
        for (int off = 32; off >= 1; off >>= 1) {
            float ov = __shfl_xor(v1, off);
            int   oi = __shfl_xor(i1, off);
            if (ov > v1 || (ov == v1 && oi < i1)) { v1 = ov; i1 = oi; }
        }
        float v2 = (lane == i1) ? -INFINITY : logit; int i2 = lane;
#pragma unroll
        for (int off = 32; off >= 1; off >>= 1) {
            float ov = __shfl_xor(v2, off);
            int   oi = __shfl_xor(i2, off);
            if (ov > v2 || (ov == v2 && oi < i2)) { v2 = ov; i2 = oi; }
        }

        float outv = (lane == i1 || lane == i2) ? gate : 0.0f;
        mask_out[(size_t)row * EEXP + lane] = outv;
        if (lane == 0) {
            idx_out[row * 2 + 0] = (float)i1;
            idx_out[row * 2 + 1] = (float)i2;
        }
    }
}

extern "C" void kernel_launch(void* const* d_in, const int* in_sizes, int n_in,
                              void* d_out, int out_size, void* d_ws, size_t ws_size,
                              hipStream_t stream) {
    const float* x = (const float*)d_in[0];
    const float* W = (const float*)d_in[1];
    const float* b = (const float*)d_in[2];
    float* mask_out = (float*)d_out;
    float* idx_out  = mask_out + (size_t)NROWS * EEXP;
    unsigned char* ws = (unsigned char*)d_ws;   // needs 768 KB

    wsplit_kernel<<<dim3(64), dim3(256), 0, stream>>>(W, ws);
    router_kernel<<<dim3(NROWS / RB), dim3(512), 0, stream>>>(x, ws, b, mask_out, idx_out);
}